// Round 5
// baseline (825.021 us; speedup 1.0000x reference)
//
#include <hip/hip_runtime.h>
#include <hip/hip_bf16.h>

typedef __attribute__((ext_vector_type(8))) short  short8;
typedef __attribute__((ext_vector_type(4))) short  short4b;
typedef __attribute__((ext_vector_type(4))) float  f32x4;

#define HIDDEN   256
#define NLAYERS  4
#define NPTS     131072
#define PPW      32                    // points per workgroup
#define NWG      (NPTS / PPW)          // 4096
#define NSTATE   5                     // h, g0, g1, gt, S=s0+s1

// workspace layout (bytes)
#define WS_PARTIALS   0                          // 4096 doubles = 32 KB
#define WS_WHI        65536
#define WPLANE_BYTES  (4 * 16 * 8 * 1024)        // 4 layers x 16 jt x 8 kt x 1KB
#define WS_WLO        (WS_WHI + WPLANE_BYTES)

__device__ __forceinline__ unsigned short f2bf(float f) {
    return __builtin_bit_cast(unsigned short, __float2bfloat16(f));   // HW RNE convert
}
__device__ __forceinline__ float bf2f(unsigned short h) {
    return __uint_as_float(((unsigned)h) << 16);
}
__device__ __forceinline__ float fast_tanh(float z) {
    float az = fabsf(z);
    float e  = __expf(2.f * az);                 // inf for big az -> r = 1, no NaN
    float r  = 1.f - __fdividef(2.f, e + 1.f);
    return copysignf(r, z);
}

// ---------------- weight prep: split W_h into bf16 hi/lo, fragment-contiguous ----------------
// Fragment (layer, jt, kt): lane l holds W[k][j] for j = jt*16 + (l&15),
// k = kt*32 + (l>>4)*8 + e (e=0..7). Used as MFMA *A*-operand (row = j, K = k).
__global__ void prep_w(const float* __restrict__ Wh,
                       unsigned short* __restrict__ whi, unsigned short* __restrict__ wlo)
{
    int b    = blockIdx.x;               // 512 = 4 layers x 16 jt x 8 kt
    int lay  = b >> 7;
    int jt   = (b >> 3) & 15;
    int kt   = b & 7;
    int lane = threadIdx.x;              // 64
    int j    = jt * 16 + (lane & 15);
    int k0   = kt * 32 + (lane >> 4) * 8;
    const float* W = Wh + (size_t)lay * HIDDEN * HIDDEN;
    size_t base = ((size_t)(lay * 16 + jt) * 8 + kt) * 512 + (size_t)lane * 8;  // ushort units
#pragma unroll
    for (int e = 0; e < 8; ++e) {
        float w = W[(size_t)(k0 + e) * HIDDEN + j];
        unsigned short h = f2bf(w);
        whi[base + e] = h;
        wlo[base + e] = f2bf(w - bf2f(h));
    }
}

// ---------------- fused PINN kernel: 512 thr (8 waves), 160 KB LDS, 1 WG/CU ----------------
// State LDS, per plane: fragment (s, ph, kt) at byte ((s*2+ph)*8 + kt)*1024, 80 KB/plane.
// Element (s, point p, k): ph = p>>4, pc = p&15:
//   byte = ((s*2+ph)*8 + (k>>5))*1024 + (((k>>3)&3)*16 + pc)*16 + (k&7)*2
// As MFMA B-operand fragment: lane l -> col (point) = l&15, k = kt*32 + (l>>4)*8 + e.
// Waves: wid = (ph<<2)|jg : jg in 0..3 owns jt = jg*4..+4 (64 j rows), ph = point half.
// MFMA: mfma(W_frag, state_frag, acc) -> D: col(lane&15)=point, row((lane>>4)*4+r)=j.
__global__ __launch_bounds__(512, 2)
void pinn_mfma(const float* __restrict__ X,
               const float* __restrict__ W_in, const float* __restrict__ b_in,
               const float* __restrict__ b_h,  const float* __restrict__ W_out,
               const unsigned short* __restrict__ whi, const unsigned short* __restrict__ wlo,
               double* __restrict__ partials)
{
    extern __shared__ char lds[];
    char*   SH  = lds;                   // 81920 B hi plane
    char*   SL  = lds + 81920;           // 81920 B lo plane
    float*  red = (float*)lds;           // aliases (s=0,ph=0,kt=0..1) tiles: 512 floats
    double* sq  = (double*)(lds + 2048); // aliases (s=0,ph=0,kt=2) tile: 32 doubles

    const int tid  = threadIdx.x;
    const int lane = tid & 63;
    const int wid  = tid >> 6;           // 0..7
    const int jg   = wid & 3;            // j-group (4 jt each)
    const int ph   = wid >> 2;           // point half (0/1)
    const int q    = lane >> 4;          // 0..3
    const int c    = lane & 15;
    const int wg   = blockIdx.x;
    const int pt0  = wg * PPW;

    // ---- input layer: thread (p = tid&31, jq0 = tid>>5) covers 4 j-quads ----
    {
        const int p   = tid & 31;
        const int jq0 = tid >> 5;                // 0..15
        const int phw = p >> 4, pc = p & 15;
        const float* xp = X + (size_t)(pt0 + p) * 3;
        const float x0 = xp[0], x1 = xp[1], x2 = xp[2];
#pragma unroll
        for (int i = 0; i < 4; ++i) {
            const int jq = jq0 + 16 * i;         // 0..63
            const int j0 = jq * 4;
            const f32x4 w0 = *(const f32x4*)(W_in + j0);
            const f32x4 w1 = *(const f32x4*)(W_in + HIDDEN + j0);
            const f32x4 w2 = *(const f32x4*)(W_in + 2 * HIDDEN + j0);
            const f32x4 bq = *(const f32x4*)(b_in + j0);
            float o[NSTATE][4];
#pragma unroll
            for (int r = 0; r < 4; ++r) {
                float z  = fmaf(x0, w0[r], fmaf(x1, w1[r], fmaf(x2, w2[r], bq[r])));
                float a  = fast_tanh(z);
                float td = 1.f - a * a;
                float m2 = -2.f * a * td;
                o[0][r] = a; o[1][r] = td * w0[r]; o[2][r] = td * w1[r]; o[3][r] = td * w2[r];
                o[4][r] = m2 * fmaf(w0[r], w0[r], w1[r] * w1[r]);
            }
            const int kt = jq >> 3, kg = (jq >> 1) & 3, e0 = (jq & 1) * 4;
            const size_t sub = (size_t)(kg * 16 + pc) * 16 + e0 * 2;
#pragma unroll
            for (int s = 0; s < NSTATE; ++s) {
                short4b hi, lo;
#pragma unroll
                for (int r = 0; r < 4; ++r) {
                    unsigned short h = f2bf(o[s][r]);
                    hi[r] = (short)h;
                    lo[r] = (short)f2bf(o[s][r] - bf2f(h));
                }
                size_t off = (size_t)((s * 2 + phw) * 8 + kt) * 1024 + sub;
                *(short4b*)(SH + off) = hi;
                *(short4b*)(SL + off) = lo;
            }
        }
    }
    __syncthreads();

    // ---- hidden layers: split-bf16 MFMA (Wh*Sh + Wl*Sh + Wh*Sl), swapped operands ----
#pragma unroll 1
    for (int l = 0; l < NLAYERS; ++l) {
        f32x4 bias[4];
#pragma unroll
        for (int jj = 0; jj < 4; ++jj)
            bias[jj] = *(const f32x4*)(b_h + l * HIDDEN + (jg * 4 + jj) * 16 + q * 4);

        f32x4 acc[4][NSTATE];
#pragma unroll
        for (int jj = 0; jj < 4; ++jj)
#pragma unroll
            for (int mt = 0; mt < NSTATE; ++mt)
                acc[jj][mt] = (f32x4){0.f, 0.f, 0.f, 0.f};

#pragma unroll 2
        for (int kt = 0; kt < 8; ++kt) {
            short8 sh_[NSTATE], sl_[NSTATE];
#pragma unroll
            for (int mt = 0; mt < NSTATE; ++mt) {
                size_t fo = (size_t)((mt * 2 + ph) * 8 + kt) * 1024 + (size_t)lane * 16;
                sh_[mt] = *(const short8*)(SH + fo);
                sl_[mt] = *(const short8*)(SL + fo);
            }
            short8 wh[4], wl[4];
#pragma unroll
            for (int jj = 0; jj < 4; ++jj) {
                size_t fo = ((size_t)(l * 16 + jg * 4 + jj) * 8 + kt) * 512 + (size_t)lane * 8;
                wh[jj] = *(const short8*)(whi + fo);
                wl[jj] = *(const short8*)(wlo + fo);
            }
            // product-major: 20 MFMAs between accumulator reuses
#pragma unroll
            for (int jj = 0; jj < 4; ++jj)
#pragma unroll
                for (int mt = 0; mt < NSTATE; ++mt)
                    acc[jj][mt] = __builtin_amdgcn_mfma_f32_16x16x32_bf16(wh[jj], sh_[mt], acc[jj][mt], 0, 0, 0);
#pragma unroll
            for (int jj = 0; jj < 4; ++jj)
#pragma unroll
                for (int mt = 0; mt < NSTATE; ++mt)
                    acc[jj][mt] = __builtin_amdgcn_mfma_f32_16x16x32_bf16(wl[jj], sh_[mt], acc[jj][mt], 0, 0, 0);
#pragma unroll
            for (int jj = 0; jj < 4; ++jj)
#pragma unroll
                for (int mt = 0; mt < NSTATE; ++mt)
                    acc[jj][mt] = __builtin_amdgcn_mfma_f32_16x16x32_bf16(wh[jj], sl_[mt], acc[jj][mt], 0, 0, 0);
        }

        __syncthreads();   // all waves done reading state

        // tanh jet chain; each thread owns 4 consecutive j per jj -> packed b64 writes
#pragma unroll
        for (int jj = 0; jj < 4; ++jj) {
            const int jt  = jg * 4 + jj;
            const int ktj = jt >> 1;
            const int kg  = (jt & 1) * 2 + (q >> 1);
            const int e0  = (q & 1) * 4;
            const size_t sub = (size_t)(kg * 16 + c) * 16 + e0 * 2;
            float o[NSTATE][4];
#pragma unroll
            for (int r = 0; r < 4; ++r) {
                float z0 = acc[jj][0][r] + bias[jj][r];
                float z1 = acc[jj][1][r], z2 = acc[jj][2][r];
                float z3 = acc[jj][3][r], zS = acc[jj][4][r];
                float a  = fast_tanh(z0);
                float td = 1.f - a * a;
                float m2 = -2.f * a * td;
                o[0][r] = a; o[1][r] = td * z1; o[2][r] = td * z2; o[3][r] = td * z3;
                o[4][r] = fmaf(td, zS, m2 * fmaf(z1, z1, z2 * z2));
            }
#pragma unroll
            for (int s = 0; s < NSTATE; ++s) {
                short4b hi, lo;
#pragma unroll
                for (int r = 0; r < 4; ++r) {
                    unsigned short h = f2bf(o[s][r]);
                    hi[r] = (short)h;
                    lo[r] = (short)f2bf(o[s][r] - bf2f(h));
                }
                size_t off = (size_t)((s * 2 + ph) * 8 + ktj) * 1024 + sub;
                *(short4b*)(SH + off) = hi;
                *(short4b*)(SL + off) = lo;
            }
        }
        __syncthreads();
    }

    // ---- output: residual_p = sum_j W_out[j]*(gt - S); reads s=3,4 tiles only ----
    {
        const int p   = tid & 31;
        const int jq0 = tid >> 5;
        const int phw = p >> 4, pc = p & 15;
        float sum = 0.f;
#pragma unroll
        for (int i = 0; i < 4; ++i) {
            const int jq = jq0 + 16 * i, j0 = jq * 4;
            const int kt = jq >> 3, kg = (jq >> 1) & 3, e0 = (jq & 1) * 4;
            const size_t sub = (size_t)(kg * 16 + pc) * 16 + e0 * 2;
            size_t o3 = (size_t)((3 * 2 + phw) * 8 + kt) * 1024 + sub;
            size_t o4 = (size_t)((4 * 2 + phw) * 8 + kt) * 1024 + sub;
            short4b gh = *(short4b*)(SH + o3), gl = *(short4b*)(SL + o3);
            short4b Sh = *(short4b*)(SH + o4), Sl = *(short4b*)(SL + o4);
            f32x4 wo = *(const f32x4*)(W_out + j0);
#pragma unroll
            for (int r = 0; r < 4; ++r) {
                float gt = bf2f((unsigned short)gh[r]) + bf2f((unsigned short)gl[r]);
                float Sv = bf2f((unsigned short)Sh[r]) + bf2f((unsigned short)Sl[r]);
                sum = fmaf(wo[r], gt - Sv, sum);
            }
        }
        red[jq0 * 32 + p] = sum;   // red aliases s=0 tiles: disjoint from s=3,4 reads
    }
    __syncthreads();
    if (tid < PPW) {
        float s = 0.f;
        for (int g = 0; g < 16; ++g) s += red[g * 32 + tid];   // fixed order
        double d = (double)s;
        sq[tid] = d * d;
    }
    __syncthreads();
    if (tid == 0) {
        double tot = 0.0;
        for (int p = 0; p < PPW; ++p) tot += sq[p];            // fixed order
        partials[wg] = tot;
    }
}

__global__ void pinn_reduce_kernel(const double* __restrict__ partials, float* __restrict__ out)
{
    __shared__ double sh[256];
    double t = 0.0;
    for (int i = 0; i < NWG / 256; ++i) t += partials[threadIdx.x * (NWG / 256) + i]; // fixed order
    sh[threadIdx.x] = t;
    __syncthreads();
    for (int ofs = 128; ofs > 0; ofs >>= 1) {
        if ((int)threadIdx.x < ofs) sh[threadIdx.x] += sh[threadIdx.x + ofs];
        __syncthreads();
    }
    if (threadIdx.x == 0) {
        out[0] = (float)(sh[0] / (double)NPTS);  // pde_loss
        out[1] = 0.f;                            // ode_loss
    }
}

extern "C" void kernel_launch(void* const* d_in, const int* in_sizes, int n_in,
                              void* d_out, int out_size, void* d_ws, size_t ws_size,
                              hipStream_t stream)
{
    const float* X     = (const float*)d_in[0];
    const float* W_in  = (const float*)d_in[1];
    const float* b_in  = (const float*)d_in[2];
    const float* W_h   = (const float*)d_in[3];
    const float* b_h   = (const float*)d_in[4];
    const float* W_out = (const float*)d_in[5];
    // d_in[6] = b_out: constant output offset, zero derivative -> unused

    double*         partials = (double*)((char*)d_ws + WS_PARTIALS);
    unsigned short* whi      = (unsigned short*)((char*)d_ws + WS_WHI);
    unsigned short* wlo      = (unsigned short*)((char*)d_ws + WS_WLO);
    float*          out      = (float*)d_out;

    const size_t lds_bytes = 163840;     // 2 x 80 KB planes = full CU LDS, 1 WG/CU
    (void)hipFuncSetAttribute((const void*)pinn_mfma,
                              hipFuncAttributeMaxDynamicSharedMemorySize, (int)lds_bytes);

    hipLaunchKernelGGL(prep_w, dim3(512), dim3(64), 0, stream, W_h, whi, wlo);
    hipLaunchKernelGGL(pinn_mfma, dim3(NWG), dim3(512), lds_bytes, stream,
                       X, W_in, b_in, b_h, W_out, whi, wlo, partials);
    hipLaunchKernelGGL(pinn_reduce_kernel, dim3(1), dim3(256), 0, stream,
                       partials, out);
}

// Round 6
// 823.323 us; speedup vs baseline: 1.0021x; 1.0021x over previous
//
#include <hip/hip_runtime.h>
#include <hip/hip_bf16.h>

typedef __attribute__((ext_vector_type(8))) short  short8;
typedef __attribute__((ext_vector_type(4))) short  short4b;
typedef __attribute__((ext_vector_type(4))) float  f32x4;

#define HIDDEN   256
#define NLAYERS  4
#define NPTS     131072
#define PPW      16
#define NWG      (NPTS / PPW)          // 8192
#define NSTATE   5                     // h, g0, g1, gt, S=s0+s1

// workspace layout (bytes)
#define WS_PARTIALS   0                          // 8192 doubles = 64 KB
#define WS_WHI        65536
#define WPLANE_BYTES  (4 * 16 * 8 * 1024)        // 4 layers x 16 jt x 8 kt x 1KB
#define WS_WLO        (WS_WHI + WPLANE_BYTES)

__device__ __forceinline__ unsigned short f2bf(float f) {
    return __builtin_bit_cast(unsigned short, __float2bfloat16(f));   // HW RNE convert
}
__device__ __forceinline__ float bf2f(unsigned short h) {
    return __uint_as_float(((unsigned)h) << 16);
}
__device__ __forceinline__ float fast_tanh(float z) {
    float az = fabsf(z);
    float e  = __expf(2.f * az);                 // inf for big az -> r = 1, no NaN
    float r  = 1.f - __fdividef(2.f, e + 1.f);
    return copysignf(r, z);
}

// ---------------- weight prep: split W_h into bf16 hi/lo, fragment-contiguous ----------------
// Fragment (layer, jt, kt): lane l holds W[k][j] for j = jt*16 + (l&15),
// k = kt*32 + (l>>4)*8 + e (e=0..7). Used as MFMA A-operand (rows = j, K = k).
__global__ void prep_w(const float* __restrict__ Wh,
                       unsigned short* __restrict__ whi, unsigned short* __restrict__ wlo)
{
    int b    = blockIdx.x;               // 512 = 4 layers x 16 jt x 8 kt
    int lay  = b >> 7;
    int jt   = (b >> 3) & 15;
    int kt   = b & 7;
    int lane = threadIdx.x;              // 64
    int j    = jt * 16 + (lane & 15);
    int k0   = kt * 32 + (lane >> 4) * 8;
    const float* W = Wh + (size_t)lay * HIDDEN * HIDDEN;
    size_t base = ((size_t)(lay * 16 + jt) * 8 + kt) * 512 + (size_t)lane * 8;  // ushort units
#pragma unroll
    for (int e = 0; e < 8; ++e) {
        float w = W[(size_t)(k0 + e) * HIDDEN + j];
        unsigned short h = f2bf(w);
        whi[base + e] = h;
        wlo[base + e] = f2bf(w - bf2f(h));
    }
}

// one GEMM K-step: consume (WHC,WLC) for k-tile kt, prefetch kt+1 into (WHN,WLN)
#define GSTEP(kt, WHC, WLC, WHN, WLN)                                               \
    {                                                                               \
        if ((kt) < 7) {                                                             \
            _Pragma("unroll") for (int jj = 0; jj < 2; ++jj) {                      \
                size_t fo = ((size_t)(l * 16 + wid * 2 + jj) * 8 + (kt) + 1) * 512  \
                            + (size_t)lane * 8;                                     \
                WHN[jj] = *(const short8*)(whi + fo);                               \
                WLN[jj] = *(const short8*)(wlo + fo);                               \
            }                                                                       \
        }                                                                           \
        short8 sh_[NSTATE], sl_[NSTATE];                                            \
        _Pragma("unroll") for (int mt = 0; mt < NSTATE; ++mt) {                     \
            size_t fo = (size_t)(mt * 8 + (kt)) * 1024 + (size_t)lane * 16;         \
            sh_[mt] = *(const short8*)(SH + fo);                                    \
            sl_[mt] = *(const short8*)(SL + fo);                                    \
        }                                                                           \
        _Pragma("unroll") for (int jj = 0; jj < 2; ++jj)                            \
            _Pragma("unroll") for (int mt = 0; mt < NSTATE; ++mt)                   \
                acc[jj][mt] = __builtin_amdgcn_mfma_f32_16x16x32_bf16(              \
                    WHC[jj], sh_[mt], acc[jj][mt], 0, 0, 0);                        \
        _Pragma("unroll") for (int jj = 0; jj < 2; ++jj)                            \
            _Pragma("unroll") for (int mt = 0; mt < NSTATE; ++mt)                   \
                acc[jj][mt] = __builtin_amdgcn_mfma_f32_16x16x32_bf16(              \
                    WLC[jj], sh_[mt], acc[jj][mt], 0, 0, 0);                        \
        _Pragma("unroll") for (int jj = 0; jj < 2; ++jj)                            \
            _Pragma("unroll") for (int mt = 0; mt < NSTATE; ++mt)                   \
                acc[jj][mt] = __builtin_amdgcn_mfma_f32_16x16x32_bf16(              \
                    WHC[jj], sl_[mt], acc[jj][mt], 0, 0, 0);                        \
    }

// ---------------- fused PINN kernel: 512 thr (8 waves), 80 KB LDS -> 2 WGs/CU ----------------
// State LDS per plane: tile (s, kt) at byte (s*8+kt)*1024, 40 KB/plane.
// Element (s, point p, k): byte = (s*8 + (k>>5))*1024 + (((k>>3)&3)*16 + p)*16 + (k&7)*2
// As MFMA B-operand: lane l -> col(point) = l&15, k = kt*32 + (l>>4)*8 + e.
// Wave wid owns j-tiles jt = wid*2, wid*2+1. mfma(W_frag, S_frag) -> D: col = point,
// row j = jt*16 + (lane>>4)*4 + reg  (4 consecutive j per lane -> packed b64 writes).
__global__ __launch_bounds__(512, 4)
void pinn_mfma(const float* __restrict__ X,
               const float* __restrict__ W_in, const float* __restrict__ b_in,
               const float* __restrict__ b_h,  const float* __restrict__ W_out,
               const unsigned short* __restrict__ whi, const unsigned short* __restrict__ wlo,
               double* __restrict__ partials)
{
    extern __shared__ char lds[];
    char*   SH  = lds;                   // 40960 B hi plane
    char*   SL  = lds + 40960;           // 40960 B lo plane
    float*  red = (float*)lds;           // aliases ch0 tiles (dead after last layer): 512 f
    double* sq  = (double*)(lds + 2048); // aliases ch0 tile kt=2: 16 doubles

    const int tid  = threadIdx.x;
    const int lane = tid & 63;
    const int wid  = tid >> 6;           // 0..7
    const int q    = lane >> 4;          // 0..3
    const int p_   = lane & 15;
    const int wg   = blockIdx.x;
    const int pt0  = wg * PPW;

    // ---- input layer: thread (p = tid&15, jq0 = tid>>4) covers 2 j-quads ----
    {
        const int p   = tid & 15;
        const int jq0 = tid >> 4;                // 0..31
        const float* xp = X + (size_t)(pt0 + p) * 3;
        const float x0 = xp[0], x1 = xp[1], x2 = xp[2];
#pragma unroll
        for (int i = 0; i < 2; ++i) {
            const int jq = jq0 + 32 * i;         // 0..63
            const int j0 = jq * 4;
            const f32x4 w0 = *(const f32x4*)(W_in + j0);
            const f32x4 w1 = *(const f32x4*)(W_in + HIDDEN + j0);
            const f32x4 w2 = *(const f32x4*)(W_in + 2 * HIDDEN + j0);
            const f32x4 bq = *(const f32x4*)(b_in + j0);
            float o[NSTATE][4];
#pragma unroll
            for (int r = 0; r < 4; ++r) {
                float z  = fmaf(x0, w0[r], fmaf(x1, w1[r], fmaf(x2, w2[r], bq[r])));
                float a  = fast_tanh(z);
                float td = 1.f - a * a;
                float m2 = -2.f * a * td;
                o[0][r] = a; o[1][r] = td * w0[r]; o[2][r] = td * w1[r]; o[3][r] = td * w2[r];
                o[4][r] = m2 * fmaf(w0[r], w0[r], w1[r] * w1[r]);
            }
            const int kt = j0 >> 5, kg = (j0 >> 3) & 3, e0 = j0 & 7;
            const size_t sub = (size_t)(kg * 16 + p) * 16 + e0 * 2;
#pragma unroll
            for (int s = 0; s < NSTATE; ++s) {
                short4b hi, lo;
#pragma unroll
                for (int r = 0; r < 4; ++r) {
                    unsigned short h = f2bf(o[s][r]);
                    hi[r] = (short)h;
                    lo[r] = (short)f2bf(o[s][r] - bf2f(h));
                }
                size_t off = (size_t)(s * 8 + kt) * 1024 + sub;
                *(short4b*)(SH + off) = hi;
                *(short4b*)(SL + off) = lo;
            }
        }
    }
    __syncthreads();

    // ---- hidden layers: split-bf16 MFMA (Wh*Sh + Wl*Sh + Wh*Sl), W prefetched ----
#pragma unroll 1
    for (int l = 0; l < NLAYERS; ++l) {
        f32x4 bias[2];
#pragma unroll
        for (int jj = 0; jj < 2; ++jj)
            bias[jj] = *(const f32x4*)(b_h + l * HIDDEN + (wid * 2 + jj) * 16 + q * 4);

        f32x4 acc[2][NSTATE];
#pragma unroll
        for (int jj = 0; jj < 2; ++jj)
#pragma unroll
            for (int mt = 0; mt < NSTATE; ++mt)
                acc[jj][mt] = (f32x4){0.f, 0.f, 0.f, 0.f};

        short8 whA[2], wlA[2], whB[2], wlB[2];
#pragma unroll
        for (int jj = 0; jj < 2; ++jj) {       // preload kt = 0
            size_t fo = ((size_t)(l * 16 + wid * 2 + jj) * 8 + 0) * 512 + (size_t)lane * 8;
            whA[jj] = *(const short8*)(whi + fo);
            wlA[jj] = *(const short8*)(wlo + fo);
        }
#pragma unroll
        for (int k2 = 0; k2 < 4; ++k2) {
            GSTEP(2 * k2,     whA, wlA, whB, wlB);
            GSTEP(2 * k2 + 1, whB, wlB, whA, wlA);
        }

        __syncthreads();   // all waves done reading state

        // tanh jet chain; lane owns 4 consecutive j per jj -> packed b64 writes
#pragma unroll
        for (int jj = 0; jj < 2; ++jj) {
            const int j0 = (wid * 2 + jj) * 16 + q * 4;
            const int kt = j0 >> 5, kg = (j0 >> 3) & 3, e0 = j0 & 7;
            const size_t sub = (size_t)(kg * 16 + p_) * 16 + e0 * 2;
            float o[NSTATE][4];
#pragma unroll
            for (int r = 0; r < 4; ++r) {
                float z0 = acc[jj][0][r] + bias[jj][r];
                float z1 = acc[jj][1][r], z2 = acc[jj][2][r];
                float z3 = acc[jj][3][r], zS = acc[jj][4][r];
                float a  = fast_tanh(z0);
                float td = 1.f - a * a;
                float m2 = -2.f * a * td;
                o[0][r] = a; o[1][r] = td * z1; o[2][r] = td * z2; o[3][r] = td * z3;
                o[4][r] = fmaf(td, zS, m2 * fmaf(z1, z1, z2 * z2));
            }
            if (l < NLAYERS - 1) {
#pragma unroll
                for (int s = 0; s < NSTATE; ++s) {
                    short4b hi, lo;
#pragma unroll
                    for (int r = 0; r < 4; ++r) {
                        unsigned short h = f2bf(o[s][r]);
                        hi[r] = (short)h;
                        lo[r] = (short)f2bf(o[s][r] - bf2f(h));
                    }
                    size_t off = (size_t)(s * 8 + kt) * 1024 + sub;
                    *(short4b*)(SH + off) = hi;
                    *(short4b*)(SL + off) = lo;
                }
            } else {            // last layer: only gt (3) and S (4) are live
#pragma unroll
                for (int s = 3; s < NSTATE; ++s) {
                    short4b hi, lo;
#pragma unroll
                    for (int r = 0; r < 4; ++r) {
                        unsigned short h = f2bf(o[s][r]);
                        hi[r] = (short)h;
                        lo[r] = (short)f2bf(o[s][r] - bf2f(h));
                    }
                    size_t off = (size_t)(s * 8 + kt) * 1024 + sub;
                    *(short4b*)(SH + off) = hi;
                    *(short4b*)(SL + off) = lo;
                }
            }
        }
        __syncthreads();
    }

    // ---- output: residual_p = sum_j W_out[j]*(gt - S); reads ch 3,4 only ----
    {
        const int p   = tid & 15;
        const int jq0 = tid >> 4;          // 0..31
        float sum = 0.f;
#pragma unroll
        for (int i = 0; i < 2; ++i) {
            const int jq = jq0 + 32 * i, j0 = jq * 4;
            const int kt = j0 >> 5, kg = (j0 >> 3) & 3, e0 = j0 & 7;
            const size_t sub = (size_t)(kg * 16 + p) * 16 + e0 * 2;
            size_t o3 = (size_t)(3 * 8 + kt) * 1024 + sub;
            size_t o4 = (size_t)(4 * 8 + kt) * 1024 + sub;
            short4b gh = *(short4b*)(SH + o3), gl = *(short4b*)(SL + o3);
            short4b Sh = *(short4b*)(SH + o4), Sl = *(short4b*)(SL + o4);
            f32x4 wo = *(const f32x4*)(W_out + j0);
#pragma unroll
            for (int r = 0; r < 4; ++r) {
                float gt = bf2f((unsigned short)gh[r]) + bf2f((unsigned short)gl[r]);
                float Sv = bf2f((unsigned short)Sh[r]) + bf2f((unsigned short)Sl[r]);
                sum = fmaf(wo[r], gt - Sv, sum);
            }
        }
        red[jq0 * 16 + p] = sum;   // red aliases ch0 tiles: disjoint from ch3/4 reads
    }
    __syncthreads();
    if (tid < PPW) {
        float s = 0.f;
        for (int g = 0; g < 32; ++g) s += red[g * 16 + tid];   // fixed order
        double d = (double)s;
        sq[tid] = d * d;
    }
    __syncthreads();
    if (tid == 0) {
        double tot = 0.0;
        for (int p = 0; p < PPW; ++p) tot += sq[p];            // fixed order
        partials[wg] = tot;
    }
}

__global__ void pinn_reduce_kernel(const double* __restrict__ partials, float* __restrict__ out)
{
    __shared__ double sh[256];
    double t = 0.0;
    for (int i = 0; i < NWG / 256; ++i) t += partials[threadIdx.x * (NWG / 256) + i]; // fixed order
    sh[threadIdx.x] = t;
    __syncthreads();
    for (int ofs = 128; ofs > 0; ofs >>= 1) {
        if ((int)threadIdx.x < ofs) sh[threadIdx.x] += sh[threadIdx.x + ofs];
        __syncthreads();
    }
    if (threadIdx.x == 0) {
        out[0] = (float)(sh[0] / (double)NPTS);  // pde_loss
        out[1] = 0.f;                            // ode_loss
    }
}

extern "C" void kernel_launch(void* const* d_in, const int* in_sizes, int n_in,
                              void* d_out, int out_size, void* d_ws, size_t ws_size,
                              hipStream_t stream)
{
    const float* X     = (const float*)d_in[0];
    const float* W_in  = (const float*)d_in[1];
    const float* b_in  = (const float*)d_in[2];
    const float* W_h   = (const float*)d_in[3];
    const float* b_h   = (const float*)d_in[4];
    const float* W_out = (const float*)d_in[5];
    // d_in[6] = b_out: constant output offset, zero derivative -> unused

    double*         partials = (double*)((char*)d_ws + WS_PARTIALS);
    unsigned short* whi      = (unsigned short*)((char*)d_ws + WS_WHI);
    unsigned short* wlo      = (unsigned short*)((char*)d_ws + WS_WLO);
    float*          out      = (float*)d_out;

    const size_t lds_bytes = 81920;      // 2 x 40 KB planes -> 2 WGs/CU
    (void)hipFuncSetAttribute((const void*)pinn_mfma,
                              hipFuncAttributeMaxDynamicSharedMemorySize, (int)lds_bytes);

    hipLaunchKernelGGL(prep_w, dim3(512), dim3(64), 0, stream, W_h, whi, wlo);
    hipLaunchKernelGGL(pinn_mfma, dim3(NWG), dim3(512), lds_bytes, stream,
                       X, W_in, b_in, b_h, W_out, whi, wlo, partials);
    hipLaunchKernelGGL(pinn_reduce_kernel, dim3(1), dim3(256), 0, stream,
                       partials, out);
}

// Round 7
// 806.440 us; speedup vs baseline: 1.0230x; 1.0209x over previous
//
#include <hip/hip_runtime.h>
#include <hip/hip_bf16.h>

typedef __attribute__((ext_vector_type(8))) short  short8;
typedef __attribute__((ext_vector_type(4))) short  short4b;
typedef __attribute__((ext_vector_type(4))) float  f32x4;

#define HIDDEN   256
#define NLAYERS  4
#define NPTS     131072
#define PPW      16
#define NWG      (NPTS / PPW)          // 8192
#define NSTATE   5                     // h, g0, g1, gt, S=s0+s1

// workspace layout (bytes)
#define WS_PARTIALS   0                          // 8192 doubles = 64 KB
#define WS_WHI        65536
#define WPLANE_BYTES  (4 * 16 * 8 * 1024)        // 4 layers x 16 jt x 8 kt x 1KB
#define WS_WLO        (WS_WHI + WPLANE_BYTES)

__device__ __forceinline__ unsigned short f2bf(float f) {
    return __builtin_bit_cast(unsigned short, __float2bfloat16(f));   // HW RNE convert
}
__device__ __forceinline__ float bf2f(unsigned short h) {
    return __uint_as_float(((unsigned)h) << 16);
}
__device__ __forceinline__ float fast_tanh(float z) {
    float az = fabsf(z);
    float e  = __expf(2.f * az);                 // inf for big az -> r = 1, no NaN
    float r  = 1.f - __fdividef(2.f, e + 1.f);
    return copysignf(r, z);
}

// ---------------- weight prep: split W_h into bf16 hi/lo, fragment-contiguous ----------------
// Fragment (layer, jt, kt): lane l holds W[k][j] for j = jt*16 + (l&15),
// k = kt*32 + (l>>4)*8 + e (e=0..7). Used as MFMA A-operand (rows = j, K = k).
__global__ void prep_w(const float* __restrict__ Wh,
                       unsigned short* __restrict__ whi, unsigned short* __restrict__ wlo)
{
    int b    = blockIdx.x;               // 512 = 4 layers x 16 jt x 8 kt
    int lay  = b >> 7;
    int jt   = (b >> 3) & 15;
    int kt   = b & 7;
    int lane = threadIdx.x;              // 64
    int j    = jt * 16 + (lane & 15);
    int k0   = kt * 32 + (lane >> 4) * 8;
    const float* W = Wh + (size_t)lay * HIDDEN * HIDDEN;
    size_t base = ((size_t)(lay * 16 + jt) * 8 + kt) * 512 + (size_t)lane * 8;  // ushort units
#pragma unroll
    for (int e = 0; e < 8; ++e) {
        float w = W[(size_t)(k0 + e) * HIDDEN + j];
        unsigned short h = f2bf(w);
        whi[base + e] = h;
        wlo[base + e] = f2bf(w - bf2f(h));
    }
}

// ---------------- fused PINN kernel: 512 thr (8 waves), 80 KB LDS -> 2 WGs/CU ----------------
// State LDS per plane: tile (s, kt) at byte (s*8+kt)*1024, 40 KB/plane.
// Element (s, point p, k): byte = (s*8 + (k>>5))*1024 + (((k>>3)&3)*16 + p)*16 + (k&7)*2
// As MFMA B-operand: lane l -> col(point) = l&15, k = kt*32 + (l>>4)*8 + e.
// Wave wid owns j-tiles jt = wid*2, wid*2+1. mfma(W_frag, S_frag) -> D: col = point,
// row j = jt*16 + (lane>>4)*4 + reg  (4 consecutive j per lane -> packed b64 writes).
__global__ __launch_bounds__(512, 4)
void pinn_mfma(const float* __restrict__ X,
               const float* __restrict__ W_in, const float* __restrict__ b_in,
               const float* __restrict__ b_h,  const float* __restrict__ W_out,
               const unsigned short* __restrict__ whi, const unsigned short* __restrict__ wlo,
               double* __restrict__ partials)
{
    extern __shared__ char lds[];
    char*   SH  = lds;                   // 40960 B hi plane
    char*   SL  = lds + 40960;           // 40960 B lo plane
    float*  red = (float*)lds;           // aliases ch0 kt=0,1 tiles (dead in output phase)
    double* sq  = (double*)(lds + 2048); // aliases ch0 kt=2 tile: 16 doubles

    const int tid  = threadIdx.x;
    const int lane = tid & 63;
    const int wid  = tid >> 6;           // 0..7
    const int q    = lane >> 4;          // 0..3
    const int p_   = lane & 15;
    const int wg   = blockIdx.x;
    const int pt0  = wg * PPW;

    // ---- input layer: thread (p = tid&15, jq0 = tid>>4) covers 2 j-quads ----
    {
        const int p   = tid & 15;
        const int jq0 = tid >> 4;                // 0..31
        const float* xp = X + (size_t)(pt0 + p) * 3;
        const float x0 = xp[0], x1 = xp[1], x2 = xp[2];
#pragma unroll
        for (int i = 0; i < 2; ++i) {
            const int jq = jq0 + 32 * i;         // 0..63
            const int j0 = jq * 4;
            const f32x4 w0 = *(const f32x4*)(W_in + j0);
            const f32x4 w1 = *(const f32x4*)(W_in + HIDDEN + j0);
            const f32x4 w2 = *(const f32x4*)(W_in + 2 * HIDDEN + j0);
            const f32x4 bq = *(const f32x4*)(b_in + j0);
            float o[NSTATE][4];
#pragma unroll
            for (int r = 0; r < 4; ++r) {
                float z  = fmaf(x0, w0[r], fmaf(x1, w1[r], fmaf(x2, w2[r], bq[r])));
                float a  = fast_tanh(z);
                float td = 1.f - a * a;
                float m2 = -2.f * a * td;
                o[0][r] = a; o[1][r] = td * w0[r]; o[2][r] = td * w1[r]; o[3][r] = td * w2[r];
                o[4][r] = m2 * fmaf(w0[r], w0[r], w1[r] * w1[r]);
            }
            const int kt = j0 >> 5, kg = (j0 >> 3) & 3, e0 = j0 & 7;
            const size_t sub = (size_t)(kg * 16 + p) * 16 + e0 * 2;
#pragma unroll
            for (int s = 0; s < NSTATE; ++s) {
                short4b hi, lo;
#pragma unroll
                for (int r = 0; r < 4; ++r) {
                    unsigned short h = f2bf(o[s][r]);
                    hi[r] = (short)h;
                    lo[r] = (short)f2bf(o[s][r] - bf2f(h));
                }
                size_t off = (size_t)(s * 8 + kt) * 1024 + sub;
                *(short4b*)(SH + off) = hi;
                *(short4b*)(SL + off) = lo;
            }
        }
    }
    __syncthreads();

    // ---- hidden layers: split-bf16 MFMA (Wh*Sh + Wl*Sh + Wh*Sl), swapped operands ----
#pragma unroll 1
    for (int l = 0; l < NLAYERS; ++l) {
        f32x4 bias[2];
#pragma unroll
        for (int jj = 0; jj < 2; ++jj)
            bias[jj] = *(const f32x4*)(b_h + l * HIDDEN + (wid * 2 + jj) * 16 + q * 4);

        f32x4 acc[2][NSTATE];
#pragma unroll
        for (int jj = 0; jj < 2; ++jj)
#pragma unroll
            for (int mt = 0; mt < NSTATE; ++mt)
                acc[jj][mt] = (f32x4){0.f, 0.f, 0.f, 0.f};

#pragma unroll 2
        for (int kt = 0; kt < 8; ++kt) {
            short8 wh[2], wl[2];
#pragma unroll
            for (int jj = 0; jj < 2; ++jj) {
                size_t fo = ((size_t)(l * 16 + wid * 2 + jj) * 8 + kt) * 512 + (size_t)lane * 8;
                wh[jj] = *(const short8*)(whi + fo);
                wl[jj] = *(const short8*)(wlo + fo);
            }
            short8 sh_[NSTATE], sl_[NSTATE];
#pragma unroll
            for (int mt = 0; mt < NSTATE; ++mt) {
                size_t fo = (size_t)(mt * 8 + kt) * 1024 + (size_t)lane * 16;
                sh_[mt] = *(const short8*)(SH + fo);
                sl_[mt] = *(const short8*)(SL + fo);
            }
            // product-major: 10 MFMAs between accumulator reuses
#pragma unroll
            for (int jj = 0; jj < 2; ++jj)
#pragma unroll
                for (int mt = 0; mt < NSTATE; ++mt)
                    acc[jj][mt] = __builtin_amdgcn_mfma_f32_16x16x32_bf16(wh[jj], sh_[mt], acc[jj][mt], 0, 0, 0);
#pragma unroll
            for (int jj = 0; jj < 2; ++jj)
#pragma unroll
                for (int mt = 0; mt < NSTATE; ++mt)
                    acc[jj][mt] = __builtin_amdgcn_mfma_f32_16x16x32_bf16(wl[jj], sh_[mt], acc[jj][mt], 0, 0, 0);
#pragma unroll
            for (int jj = 0; jj < 2; ++jj)
#pragma unroll
                for (int mt = 0; mt < NSTATE; ++mt)
                    acc[jj][mt] = __builtin_amdgcn_mfma_f32_16x16x32_bf16(wh[jj], sl_[mt], acc[jj][mt], 0, 0, 0);
        }

        __syncthreads();   // all waves done reading state

        // tanh jet chain; lane owns 4 consecutive j per jj -> packed b64 writes
#pragma unroll
        for (int jj = 0; jj < 2; ++jj) {
            const int j0 = (wid * 2 + jj) * 16 + q * 4;
            const int kt = j0 >> 5, kg = (j0 >> 3) & 3, e0 = j0 & 7;
            const size_t sub = (size_t)(kg * 16 + p_) * 16 + e0 * 2;
            float o[NSTATE][4];
#pragma unroll
            for (int r = 0; r < 4; ++r) {
                float z0 = acc[jj][0][r] + bias[jj][r];
                float z1 = acc[jj][1][r], z2 = acc[jj][2][r];
                float z3 = acc[jj][3][r], zS = acc[jj][4][r];
                float a  = fast_tanh(z0);
                float td = 1.f - a * a;
                float m2 = -2.f * a * td;
                o[0][r] = a; o[1][r] = td * z1; o[2][r] = td * z2; o[3][r] = td * z3;
                o[4][r] = fmaf(td, zS, m2 * fmaf(z1, z1, z2 * z2));
            }
            if (l < NLAYERS - 1) {
#pragma unroll
                for (int s = 0; s < NSTATE; ++s) {
                    short4b hi, lo;
#pragma unroll
                    for (int r = 0; r < 4; ++r) {
                        unsigned short h = f2bf(o[s][r]);
                        hi[r] = (short)h;
                        lo[r] = (short)f2bf(o[s][r] - bf2f(h));
                    }
                    size_t off = (size_t)(s * 8 + kt) * 1024 + sub;
                    *(short4b*)(SH + off) = hi;
                    *(short4b*)(SL + off) = lo;
                }
            } else {            // last layer: only gt (3) and S (4) are live
#pragma unroll
                for (int s = 3; s < NSTATE; ++s) {
                    short4b hi, lo;
#pragma unroll
                    for (int r = 0; r < 4; ++r) {
                        unsigned short h = f2bf(o[s][r]);
                        hi[r] = (short)h;
                        lo[r] = (short)f2bf(o[s][r] - bf2f(h));
                    }
                    size_t off = (size_t)(s * 8 + kt) * 1024 + sub;
                    *(short4b*)(SH + off) = hi;
                    *(short4b*)(SL + off) = lo;
                }
            }
        }
        __syncthreads();
    }

    // ---- output: residual_p = sum_j W_out[j]*(gt - S); reads ch 3,4 only ----
    {
        const int p   = tid & 15;
        const int jq0 = tid >> 4;          // 0..31
        float sum = 0.f;
#pragma unroll
        for (int i = 0; i < 2; ++i) {
            const int jq = jq0 + 32 * i, j0 = jq * 4;
            const int kt = j0 >> 5, kg = (j0 >> 3) & 3, e0 = j0 & 7;
            const size_t sub = (size_t)(kg * 16 + p) * 16 + e0 * 2;
            size_t o3 = (size_t)(3 * 8 + kt) * 1024 + sub;
            size_t o4 = (size_t)(4 * 8 + kt) * 1024 + sub;
            short4b gh = *(short4b*)(SH + o3), gl = *(short4b*)(SL + o3);
            short4b Sh = *(short4b*)(SH + o4), Sl = *(short4b*)(SL + o4);
            f32x4 wo = *(const f32x4*)(W_out + j0);
#pragma unroll
            for (int r = 0; r < 4; ++r) {
                float gt = bf2f((unsigned short)gh[r]) + bf2f((unsigned short)gl[r]);
                float Sv = bf2f((unsigned short)Sh[r]) + bf2f((unsigned short)Sl[r]);
                sum = fmaf(wo[r], gt - Sv, sum);
            }
        }
        red[jq0 * 16 + p] = sum;   // red aliases ch0 tiles: disjoint from ch3/4 reads
    }
    __syncthreads();
    if (tid < PPW) {
        float s = 0.f;
        for (int g = 0; g < 32; ++g) s += red[g * 16 + tid];   // fixed order
        double d = (double)s;
        sq[tid] = d * d;
    }
    __syncthreads();
    if (tid == 0) {
        double tot = 0.0;
        for (int p = 0; p < PPW; ++p) tot += sq[p];            // fixed order
        partials[wg] = tot;
    }
}

__global__ void pinn_reduce_kernel(const double* __restrict__ partials, float* __restrict__ out)
{
    __shared__ double sh[256];
    double t = 0.0;
    for (int i = 0; i < NWG / 256; ++i) t += partials[threadIdx.x * (NWG / 256) + i]; // fixed order
    sh[threadIdx.x] = t;
    __syncthreads();
    for (int ofs = 128; ofs > 0; ofs >>= 1) {
        if ((int)threadIdx.x < ofs) sh[threadIdx.x] += sh[threadIdx.x + ofs];
        __syncthreads();
    }
    if (threadIdx.x == 0) {
        out[0] = (float)(sh[0] / (double)NPTS);  // pde_loss
        out[1] = 0.f;                            // ode_loss
    }
}

extern "C" void kernel_launch(void* const* d_in, const int* in_sizes, int n_in,
                              void* d_out, int out_size, void* d_ws, size_t ws_size,
                              hipStream_t stream)
{
    const float* X     = (const float*)d_in[0];
    const float* W_in  = (const float*)d_in[1];
    const float* b_in  = (const float*)d_in[2];
    const float* W_h   = (const float*)d_in[3];
    const float* b_h   = (const float*)d_in[4];
    const float* W_out = (const float*)d_in[5];
    // d_in[6] = b_out: constant output offset, zero derivative -> unused

    double*         partials = (double*)((char*)d_ws + WS_PARTIALS);
    unsigned short* whi      = (unsigned short*)((char*)d_ws + WS_WHI);
    unsigned short* wlo      = (unsigned short*)((char*)d_ws + WS_WLO);
    float*          out      = (float*)d_out;

    const size_t lds_bytes = 81920;      // 2 x 40 KB planes -> 2 WGs/CU
    (void)hipFuncSetAttribute((const void*)pinn_mfma,
                              hipFuncAttributeMaxDynamicSharedMemorySize, (int)lds_bytes);

    hipLaunchKernelGGL(prep_w, dim3(512), dim3(64), 0, stream, W_h, whi, wlo);
    hipLaunchKernelGGL(pinn_mfma, dim3(NWG), dim3(512), lds_bytes, stream,
                       X, W_in, b_in, b_h, W_out, whi, wlo, partials);
    hipLaunchKernelGGL(pinn_reduce_kernel, dim3(1), dim3(256), 0, stream,
                       partials, out);
}

// Round 8
// 570.019 us; speedup vs baseline: 1.4474x; 1.4148x over previous
//
#include <hip/hip_runtime.h>
#include <hip/hip_bf16.h>

typedef __attribute__((ext_vector_type(8))) short  short8;
typedef __attribute__((ext_vector_type(4))) short  short4b;
typedef __attribute__((ext_vector_type(4))) float  f32x4;

#define HIDDEN   256
#define NLAYERS  4
#define NPTS     131072
#define PPW      16
#define NWG      (NPTS / PPW)          // 8192
#define NSTATE   5                     // h, g0, g1, gt, S=s0+s1

// workspace layout (bytes)
#define WS_PARTIALS   0                          // 8192 doubles = 64 KB
#define WS_WHI        65536
#define WPLANE_BYTES  (4 * 16 * 8 * 1024)        // 4 layers x 16 jt x 8 kt x 1KB
#define WS_WLO        (WS_WHI + WPLANE_BYTES)

__device__ __forceinline__ unsigned short f2bf(float f) {
    return __builtin_bit_cast(unsigned short, __float2bfloat16(f));   // HW RNE convert
}
__device__ __forceinline__ float bf2f(unsigned short h) {
    return __uint_as_float(((unsigned)h) << 16);
}
__device__ __forceinline__ float fast_tanh(float z) {
    float az = fabsf(z);
    float e  = __expf(2.f * az);                 // inf for big az -> r = 1, no NaN
    float r  = 1.f - __fdividef(2.f, e + 1.f);
    return copysignf(r, z);
}

// ---------------- weight prep: split W_h into bf16 hi/lo, fragment-contiguous ----------------
// Fragment (layer, jt, kt): lane l holds W[k][j] for j = jt*16 + (l&15),
// k = kt*32 + (l>>4)*8 + e (e=0..7). Used as MFMA A-operand (rows = j, K = k).
// W stays split (wh + wl products) so weights act at ~fp32 precision; only the
// activations/jet states are bf16 (standard mixed-precision regime).
__global__ void prep_w(const float* __restrict__ Wh,
                       unsigned short* __restrict__ whi, unsigned short* __restrict__ wlo)
{
    int b    = blockIdx.x;               // 512 = 4 layers x 16 jt x 8 kt
    int lay  = b >> 7;
    int jt   = (b >> 3) & 15;
    int kt   = b & 7;
    int lane = threadIdx.x;              // 64
    int j    = jt * 16 + (lane & 15);
    int k0   = kt * 32 + (lane >> 4) * 8;
    const float* W = Wh + (size_t)lay * HIDDEN * HIDDEN;
    size_t base = ((size_t)(lay * 16 + jt) * 8 + kt) * 512 + (size_t)lane * 8;  // ushort units
#pragma unroll
    for (int e = 0; e < 8; ++e) {
        float w = W[(size_t)(k0 + e) * HIDDEN + j];
        unsigned short h = f2bf(w);
        whi[base + e] = h;
        wlo[base + e] = f2bf(w - bf2f(h));
    }
}

// ---------------- fused PINN kernel: 512 thr (8 waves), 40 KB LDS, 2 WGs/CU ----------------
// State LDS (single bf16 plane): tile (s, kt) at byte (s*8+kt)*1024, 40 KB total.
// Element (s, point p, k): byte = (s*8 + (k>>5))*1024 + (((k>>3)&3)*16 + p)*16 + (k&7)*2
// As MFMA B-operand: lane l -> col(point) = l&15, k = kt*32 + (l>>4)*8 + e.
// Wave wid owns j-tiles jt = wid*2, wid*2+1. mfma(W_frag, S_frag) -> D: col = point,
// row j = jt*16 + (lane>>4)*4 + reg  (4 consecutive j per lane -> packed b64 writes).
__global__ __launch_bounds__(512, 4)
void pinn_mfma(const float* __restrict__ X,
               const float* __restrict__ W_in, const float* __restrict__ b_in,
               const float* __restrict__ b_h,  const float* __restrict__ W_out,
               const unsigned short* __restrict__ whi, const unsigned short* __restrict__ wlo,
               double* __restrict__ partials)
{
    extern __shared__ char lds[];
    char*   SH  = lds;                   // 40960 B bf16 state plane
    float*  red = (float*)lds;           // aliases ch0 kt=0,1 tiles (dead in output phase)
    double* sq  = (double*)(lds + 2048); // aliases ch0 kt=2 tile: 16 doubles

    const int tid  = threadIdx.x;
    const int lane = tid & 63;
    const int wid  = tid >> 6;           // 0..7
    const int q    = lane >> 4;          // 0..3
    const int p_   = lane & 15;
    const int wg   = blockIdx.x;
    const int pt0  = wg * PPW;

    // ---- input layer: thread (p = tid&15, jq0 = tid>>4) covers 2 j-quads ----
    {
        const int p   = tid & 15;
        const int jq0 = tid >> 4;                // 0..31
        const float* xp = X + (size_t)(pt0 + p) * 3;
        const float x0 = xp[0], x1 = xp[1], x2 = xp[2];
#pragma unroll
        for (int i = 0; i < 2; ++i) {
            const int jq = jq0 + 32 * i;         // 0..63
            const int j0 = jq * 4;
            const f32x4 w0 = *(const f32x4*)(W_in + j0);
            const f32x4 w1 = *(const f32x4*)(W_in + HIDDEN + j0);
            const f32x4 w2 = *(const f32x4*)(W_in + 2 * HIDDEN + j0);
            const f32x4 bq = *(const f32x4*)(b_in + j0);
            float o[NSTATE][4];
#pragma unroll
            for (int r = 0; r < 4; ++r) {
                float z  = fmaf(x0, w0[r], fmaf(x1, w1[r], fmaf(x2, w2[r], bq[r])));
                float a  = fast_tanh(z);
                float td = 1.f - a * a;
                float m2 = -2.f * a * td;
                o[0][r] = a; o[1][r] = td * w0[r]; o[2][r] = td * w1[r]; o[3][r] = td * w2[r];
                o[4][r] = m2 * fmaf(w0[r], w0[r], w1[r] * w1[r]);
            }
            const int kt = j0 >> 5, kg = (j0 >> 3) & 3, e0 = j0 & 7;
            const size_t sub = (size_t)(kg * 16 + p) * 16 + e0 * 2;
#pragma unroll
            for (int s = 0; s < NSTATE; ++s) {
                short4b hi;
#pragma unroll
                for (int r = 0; r < 4; ++r) hi[r] = (short)f2bf(o[s][r]);
                *(short4b*)(SH + (size_t)(s * 8 + kt) * 1024 + sub) = hi;
            }
        }
    }
    __syncthreads();

    // ---- hidden layers: MFMA GEMM, W split (wh + wl), bf16 states ----
#pragma unroll 1
    for (int l = 0; l < NLAYERS; ++l) {
        f32x4 bias[2];
#pragma unroll
        for (int jj = 0; jj < 2; ++jj)
            bias[jj] = *(const f32x4*)(b_h + l * HIDDEN + (wid * 2 + jj) * 16 + q * 4);

        f32x4 acc[2][NSTATE];
#pragma unroll
        for (int jj = 0; jj < 2; ++jj)
#pragma unroll
            for (int mt = 0; mt < NSTATE; ++mt)
                acc[jj][mt] = (f32x4){0.f, 0.f, 0.f, 0.f};

#pragma unroll 2
        for (int kt = 0; kt < 8; ++kt) {
            short8 wh[2], wl[2];
#pragma unroll
            for (int jj = 0; jj < 2; ++jj) {
                size_t fo = ((size_t)(l * 16 + wid * 2 + jj) * 8 + kt) * 512 + (size_t)lane * 8;
                wh[jj] = *(const short8*)(whi + fo);
                wl[jj] = *(const short8*)(wlo + fo);
            }
            short8 sh_[NSTATE];
#pragma unroll
            for (int mt = 0; mt < NSTATE; ++mt)
                sh_[mt] = *(const short8*)(SH + (size_t)(mt * 8 + kt) * 1024 + (size_t)lane * 16);

            __builtin_amdgcn_s_setprio(1);
            // product-major: 10 MFMAs between accumulator reuses
#pragma unroll
            for (int jj = 0; jj < 2; ++jj)
#pragma unroll
                for (int mt = 0; mt < NSTATE; ++mt)
                    acc[jj][mt] = __builtin_amdgcn_mfma_f32_16x16x32_bf16(wh[jj], sh_[mt], acc[jj][mt], 0, 0, 0);
#pragma unroll
            for (int jj = 0; jj < 2; ++jj)
#pragma unroll
                for (int mt = 0; mt < NSTATE; ++mt)
                    acc[jj][mt] = __builtin_amdgcn_mfma_f32_16x16x32_bf16(wl[jj], sh_[mt], acc[jj][mt], 0, 0, 0);
            __builtin_amdgcn_s_setprio(0);
        }

        __syncthreads();   // all waves done reading state

        // tanh jet chain; lane owns 4 consecutive j per jj -> packed b64 writes
#pragma unroll
        for (int jj = 0; jj < 2; ++jj) {
            const int j0 = (wid * 2 + jj) * 16 + q * 4;
            const int kt = j0 >> 5, kg = (j0 >> 3) & 3, e0 = j0 & 7;
            const size_t sub = (size_t)(kg * 16 + p_) * 16 + e0 * 2;
            float o[NSTATE][4];
#pragma unroll
            for (int r = 0; r < 4; ++r) {
                float z0 = acc[jj][0][r] + bias[jj][r];
                float z1 = acc[jj][1][r], z2 = acc[jj][2][r];
                float z3 = acc[jj][3][r], zS = acc[jj][4][r];
                float a  = fast_tanh(z0);
                float td = 1.f - a * a;
                float m2 = -2.f * a * td;
                o[0][r] = a; o[1][r] = td * z1; o[2][r] = td * z2; o[3][r] = td * z3;
                o[4][r] = fmaf(td, zS, m2 * fmaf(z1, z1, z2 * z2));
            }
            const int sLo = (l < NLAYERS - 1) ? 0 : 3;   // last layer: only gt,S live
#pragma unroll
            for (int s = 0; s < NSTATE; ++s) {
                if (s < sLo) continue;
                short4b hi;
#pragma unroll
                for (int r = 0; r < 4; ++r) hi[r] = (short)f2bf(o[s][r]);
                *(short4b*)(SH + (size_t)(s * 8 + kt) * 1024 + sub) = hi;
            }
        }
        __syncthreads();
    }

    // ---- output: residual_p = sum_j W_out[j]*(gt - S); reads ch 3,4 only ----
    {
        const int p   = tid & 15;
        const int jq0 = tid >> 4;          // 0..31
        float sum = 0.f;
#pragma unroll
        for (int i = 0; i < 2; ++i) {
            const int jq = jq0 + 32 * i, j0 = jq * 4;
            const int kt = j0 >> 5, kg = (j0 >> 3) & 3, e0 = j0 & 7;
            const size_t sub = (size_t)(kg * 16 + p) * 16 + e0 * 2;
            short4b gh = *(short4b*)(SH + (size_t)(3 * 8 + kt) * 1024 + sub);
            short4b Sh = *(short4b*)(SH + (size_t)(4 * 8 + kt) * 1024 + sub);
            f32x4 wo = *(const f32x4*)(W_out + j0);
#pragma unroll
            for (int r = 0; r < 4; ++r)
                sum = fmaf(wo[r], bf2f((unsigned short)gh[r]) - bf2f((unsigned short)Sh[r]), sum);
        }
        red[jq0 * 16 + p] = sum;   // red aliases ch0 tiles: disjoint from ch3/4 reads
    }
    __syncthreads();
    if (tid < PPW) {
        float s = 0.f;
        for (int g = 0; g < 32; ++g) s += red[g * 16 + tid];   // fixed order
        double d = (double)s;
        sq[tid] = d * d;
    }
    __syncthreads();
    if (tid == 0) {
        double tot = 0.0;
        for (int p = 0; p < PPW; ++p) tot += sq[p];            // fixed order
        partials[wg] = tot;
    }
}

__global__ void pinn_reduce_kernel(const double* __restrict__ partials, float* __restrict__ out)
{
    __shared__ double sh[256];
    double t = 0.0;
    for (int i = 0; i < NWG / 256; ++i) t += partials[threadIdx.x * (NWG / 256) + i]; // fixed order
    sh[threadIdx.x] = t;
    __syncthreads();
    for (int ofs = 128; ofs > 0; ofs >>= 1) {
        if ((int)threadIdx.x < ofs) sh[threadIdx.x] += sh[threadIdx.x + ofs];
        __syncthreads();
    }
    if (threadIdx.x == 0) {
        out[0] = (float)(sh[0] / (double)NPTS);  // pde_loss
        out[1] = 0.f;                            // ode_loss
    }
}

extern "C" void kernel_launch(void* const* d_in, const int* in_sizes, int n_in,
                              void* d_out, int out_size, void* d_ws, size_t ws_size,
                              hipStream_t stream)
{
    const float* X     = (const float*)d_in[0];
    const float* W_in  = (const float*)d_in[1];
    const float* b_in  = (const float*)d_in[2];
    const float* W_h   = (const float*)d_in[3];
    const float* b_h   = (const float*)d_in[4];
    const float* W_out = (const float*)d_in[5];
    // d_in[6] = b_out: constant output offset, zero derivative -> unused

    double*         partials = (double*)((char*)d_ws + WS_PARTIALS);
    unsigned short* whi      = (unsigned short*)((char*)d_ws + WS_WHI);
    unsigned short* wlo      = (unsigned short*)((char*)d_ws + WS_WLO);
    float*          out      = (float*)d_out;

    const size_t lds_bytes = 40960;      // single bf16 state plane -> 2+ WGs/CU
    (void)hipFuncSetAttribute((const void*)pinn_mfma,
                              hipFuncAttributeMaxDynamicSharedMemorySize, (int)lds_bytes);

    hipLaunchKernelGGL(prep_w, dim3(512), dim3(64), 0, stream, W_h, whi, wlo);
    hipLaunchKernelGGL(pinn_mfma, dim3(NWG), dim3(512), lds_bytes, stream,
                       X, W_in, b_in, b_h, W_out, whi, wlo, partials);
    hipLaunchKernelGGL(pinn_reduce_kernel, dim3(1), dim3(256), 0, stream,
                       partials, out);
}

// Round 9
// 563.200 us; speedup vs baseline: 1.4649x; 1.0121x over previous
//
#include <hip/hip_runtime.h>
#include <hip/hip_bf16.h>

typedef __attribute__((ext_vector_type(8))) short  short8;
typedef __attribute__((ext_vector_type(4))) short  short4b;
typedef __attribute__((ext_vector_type(4))) float  f32x4;

#define HIDDEN   256
#define NLAYERS  4
#define NPTS     131072
#define PPW      16
#define NWG      (NPTS / PPW)          // 8192
#define NSTATE   5                     // h, g0, g1, gt, S=s0+s1
#define PLANE    40960                 // bytes per state plane (5*8 tiles x 1KB)

// workspace layout (bytes)
#define WS_PARTIALS   0                          // 8192 doubles = 64 KB
#define WS_WHI        65536
#define WPLANE_BYTES  (4 * 16 * 8 * 1024)        // 4 layers x 16 jt x 8 kt x 1KB
#define WS_WLO        (WS_WHI + WPLANE_BYTES)

__device__ __forceinline__ unsigned short f2bf(float f) {
    return __builtin_bit_cast(unsigned short, __float2bfloat16(f));   // HW RNE convert
}
__device__ __forceinline__ float bf2f(unsigned short h) {
    return __uint_as_float(((unsigned)h) << 16);
}
__device__ __forceinline__ float fast_tanh(float z) {
    // tanh(z) = 1 - 2/(exp(2z)+1): exact at both saturations, no NaN, no abs/copysign
    float e = __expf(2.f * z);
    return 1.f - __fdividef(2.f, e + 1.f);
}

// ---------------- weight prep: split W_h into bf16 hi/lo, fragment-contiguous ----------------
// Fragment (layer, jt, kt): lane l holds W[k][j] for j = jt*16 + (l&15),
// k = kt*32 + (l>>4)*8 + e (e=0..7). Used as MFMA A-operand (rows = j, K = k).
// W stays split (wh + wl products, ~fp32 weight precision); states are bf16.
__global__ void prep_w(const float* __restrict__ Wh,
                       unsigned short* __restrict__ whi, unsigned short* __restrict__ wlo)
{
    int b    = blockIdx.x;               // 512 = 4 layers x 16 jt x 8 kt
    int lay  = b >> 7;
    int jt   = (b >> 3) & 15;
    int kt   = b & 7;
    int lane = threadIdx.x;              // 64
    int j    = jt * 16 + (lane & 15);
    int k0   = kt * 32 + (lane >> 4) * 8;
    const float* W = Wh + (size_t)lay * HIDDEN * HIDDEN;
    size_t base = ((size_t)(lay * 16 + jt) * 8 + kt) * 512 + (size_t)lane * 8;  // ushort units
#pragma unroll
    for (int e = 0; e < 8; ++e) {
        float w = W[(size_t)(k0 + e) * HIDDEN + j];
        unsigned short h = f2bf(w);
        whi[base + e] = h;
        wlo[base + e] = f2bf(w - bf2f(h));
    }
}

// ---------------- fused PINN kernel: 512 thr (8 waves), 80 KB LDS, 2 WGs/CU ----------------
// Ping-pong bf16 state planes P0/P1 (40 KB each): layer l reads P(l&1), writes P(~l&1);
// ONE barrier per layer (after tanh writes). WAR on the reused plane is ordered
// transitively through the previous layer's barrier.
// Plane layout: tile (s, kt) at byte (s*8+kt)*1024.
// Element (s, point p, k): byte = (s*8 + (k>>5))*1024 + (((k>>3)&3)*16 + p)*16 + (k&7)*2
// As MFMA B-operand: lane l -> col(point) = l&15, k = kt*32 + (l>>4)*8 + e.
// Wave wid owns j-tiles jt = wid*2, wid*2+1. mfma(W_frag, S_frag) -> D: col = point,
// row j = jt*16 + (lane>>4)*4 + reg  (4 consecutive j per lane -> packed b64 writes).
__global__ __launch_bounds__(512, 4)
void pinn_mfma(const float* __restrict__ X,
               const float* __restrict__ W_in, const float* __restrict__ b_in,
               const float* __restrict__ b_h,  const float* __restrict__ W_out,
               const unsigned short* __restrict__ whi, const unsigned short* __restrict__ wlo,
               double* __restrict__ partials)
{
    extern __shared__ char lds[];
    char*   P0  = lds;                        // 40960 B plane (layers 0,2 read; input writes)
    char*   P1  = lds + PLANE;                // 40960 B plane (layers 1,3 read)
    float*  red = (float*)P1;                 // aliases P1 ch0 tiles (dead in output phase)
    double* sq  = (double*)(P1 + 2048);       // aliases P1 ch0 kt=2 tile: 16 doubles

    const int tid  = threadIdx.x;
    const int lane = tid & 63;
    const int wid  = tid >> 6;           // 0..7
    const int q    = lane >> 4;          // 0..3
    const int p_   = lane & 15;
    const int wg   = blockIdx.x;
    const int pt0  = wg * PPW;

    // ---- input layer -> P0: thread (p = tid&15, jq0 = tid>>4) covers 2 j-quads ----
    {
        const int p   = tid & 15;
        const int jq0 = tid >> 4;                // 0..31
        const float* xp = X + (size_t)(pt0 + p) * 3;
        const float x0 = xp[0], x1 = xp[1], x2 = xp[2];
#pragma unroll
        for (int i = 0; i < 2; ++i) {
            const int jq = jq0 + 32 * i;         // 0..63
            const int j0 = jq * 4;
            const f32x4 w0 = *(const f32x4*)(W_in + j0);
            const f32x4 w1 = *(const f32x4*)(W_in + HIDDEN + j0);
            const f32x4 w2 = *(const f32x4*)(W_in + 2 * HIDDEN + j0);
            const f32x4 bq = *(const f32x4*)(b_in + j0);
            float o[NSTATE][4];
#pragma unroll
            for (int r = 0; r < 4; ++r) {
                float z  = fmaf(x0, w0[r], fmaf(x1, w1[r], fmaf(x2, w2[r], bq[r])));
                float a  = fast_tanh(z);
                float td = 1.f - a * a;
                float m2 = -2.f * a * td;
                o[0][r] = a; o[1][r] = td * w0[r]; o[2][r] = td * w1[r]; o[3][r] = td * w2[r];
                o[4][r] = m2 * fmaf(w0[r], w0[r], w1[r] * w1[r]);
            }
            const int kt = j0 >> 5, kg = (j0 >> 3) & 3, e0 = j0 & 7;
            const size_t sub = (size_t)(kg * 16 + p) * 16 + e0 * 2;
#pragma unroll
            for (int s = 0; s < NSTATE; ++s) {
                short4b hi;
#pragma unroll
                for (int r = 0; r < 4; ++r) hi[r] = (short)f2bf(o[s][r]);
                *(short4b*)(P0 + (size_t)(s * 8 + kt) * 1024 + sub) = hi;
            }
        }
    }
    __syncthreads();

    // ---- hidden layers: MFMA GEMM, W split (wh + wl), bf16 states, ping-pong planes ----
#pragma unroll 1
    for (int l = 0; l < NLAYERS; ++l) {
        char* SP  = (l & 1) ? P1 : P0;   // read plane
        char* SPn = (l & 1) ? P0 : P1;   // write plane

        f32x4 bias[2];
#pragma unroll
        for (int jj = 0; jj < 2; ++jj)
            bias[jj] = *(const f32x4*)(b_h + l * HIDDEN + (wid * 2 + jj) * 16 + q * 4);

        f32x4 acc[2][NSTATE];
#pragma unroll
        for (int jj = 0; jj < 2; ++jj)
#pragma unroll
            for (int mt = 0; mt < NSTATE; ++mt)
                acc[jj][mt] = (f32x4){0.f, 0.f, 0.f, 0.f};

#pragma unroll 2
        for (int kt = 0; kt < 8; ++kt) {
            short8 wh[2], wl[2];
#pragma unroll
            for (int jj = 0; jj < 2; ++jj) {
                size_t fo = ((size_t)(l * 16 + wid * 2 + jj) * 8 + kt) * 512 + (size_t)lane * 8;
                wh[jj] = *(const short8*)(whi + fo);
                wl[jj] = *(const short8*)(wlo + fo);
            }
            short8 sh_[NSTATE];
#pragma unroll
            for (int mt = 0; mt < NSTATE; ++mt)
                sh_[mt] = *(const short8*)(SP + (size_t)(mt * 8 + kt) * 1024 + (size_t)lane * 16);

            __builtin_amdgcn_s_setprio(1);
            // product-major: 10 MFMAs between accumulator reuses
#pragma unroll
            for (int jj = 0; jj < 2; ++jj)
#pragma unroll
                for (int mt = 0; mt < NSTATE; ++mt)
                    acc[jj][mt] = __builtin_amdgcn_mfma_f32_16x16x32_bf16(wh[jj], sh_[mt], acc[jj][mt], 0, 0, 0);
#pragma unroll
            for (int jj = 0; jj < 2; ++jj)
#pragma unroll
                for (int mt = 0; mt < NSTATE; ++mt)
                    acc[jj][mt] = __builtin_amdgcn_mfma_f32_16x16x32_bf16(wl[jj], sh_[mt], acc[jj][mt], 0, 0, 0);
            __builtin_amdgcn_s_setprio(0);
        }

        // NO barrier here: tanh writes go to the other plane (ping-pong kills the WAR)

        // tanh jet chain; lane owns 4 consecutive j per jj -> packed b64 writes
#pragma unroll
        for (int jj = 0; jj < 2; ++jj) {
            const int j0 = (wid * 2 + jj) * 16 + q * 4;
            const int kt = j0 >> 5, kg = (j0 >> 3) & 3, e0 = j0 & 7;
            const size_t sub = (size_t)(kg * 16 + p_) * 16 + e0 * 2;
            float o[NSTATE][4];
#pragma unroll
            for (int r = 0; r < 4; ++r) {
                float z0 = acc[jj][0][r] + bias[jj][r];
                float z1 = acc[jj][1][r], z2 = acc[jj][2][r];
                float z3 = acc[jj][3][r], zS = acc[jj][4][r];
                float a  = fast_tanh(z0);
                float td = 1.f - a * a;
                float m2 = -2.f * a * td;
                o[0][r] = a; o[1][r] = td * z1; o[2][r] = td * z2; o[3][r] = td * z3;
                o[4][r] = fmaf(td, zS, m2 * fmaf(z1, z1, z2 * z2));
            }
            const int sLo = (l < NLAYERS - 1) ? 0 : 3;   // last layer: only gt,S live
#pragma unroll
            for (int s = 0; s < NSTATE; ++s) {
                if (s < sLo) continue;
                short4b hi;
#pragma unroll
                for (int r = 0; r < 4; ++r) hi[r] = (short)f2bf(o[s][r]);
                *(short4b*)(SPn + (size_t)(s * 8 + kt) * 1024 + sub) = hi;
            }
        }
        __syncthreads();   // RAW: next layer's GEMM (or output phase) reads SPn
    }

    // ---- output: residual_p = sum_j W_out[j]*(gt - S); reads P0 ch 3,4 only ----
    {
        const int p   = tid & 15;
        const int jq0 = tid >> 4;          // 0..31
        float sum = 0.f;
#pragma unroll
        for (int i = 0; i < 2; ++i) {
            const int jq = jq0 + 32 * i, j0 = jq * 4;
            const int kt = j0 >> 5, kg = (j0 >> 3) & 3, e0 = j0 & 7;
            const size_t sub = (size_t)(kg * 16 + p) * 16 + e0 * 2;
            short4b gh = *(short4b*)(P0 + (size_t)(3 * 8 + kt) * 1024 + sub);
            short4b Sh = *(short4b*)(P0 + (size_t)(4 * 8 + kt) * 1024 + sub);
            f32x4 wo = *(const f32x4*)(W_out + j0);
#pragma unroll
            for (int r = 0; r < 4; ++r)
                sum = fmaf(wo[r], bf2f((unsigned short)gh[r]) - bf2f((unsigned short)Sh[r]), sum);
        }
        red[jq0 * 16 + p] = sum;   // red aliases P1 (fully dead after layer 3)
    }
    __syncthreads();
    if (tid < PPW) {
        float s = 0.f;
        for (int g = 0; g < 32; ++g) s += red[g * 16 + tid];   // fixed order
        double d = (double)s;
        sq[tid] = d * d;
    }
    __syncthreads();
    if (tid == 0) {
        double tot = 0.0;
        for (int p = 0; p < PPW; ++p) tot += sq[p];            // fixed order
        partials[wg] = tot;
    }
}

__global__ void pinn_reduce_kernel(const double* __restrict__ partials, float* __restrict__ out)
{
    __shared__ double sh[256];
    double t = 0.0;
    for (int i = 0; i < NWG / 256; ++i) t += partials[threadIdx.x * (NWG / 256) + i]; // fixed order
    sh[threadIdx.x] = t;
    __syncthreads();
    for (int ofs = 128; ofs > 0; ofs >>= 1) {
        if ((int)threadIdx.x < ofs) sh[threadIdx.x] += sh[threadIdx.x + ofs];
        __syncthreads();
    }
    if (threadIdx.x == 0) {
        out[0] = (float)(sh[0] / (double)NPTS);  // pde_loss
        out[1] = 0.f;                            // ode_loss
    }
}

extern "C" void kernel_launch(void* const* d_in, const int* in_sizes, int n_in,
                              void* d_out, int out_size, void* d_ws, size_t ws_size,
                              hipStream_t stream)
{
    const float* X     = (const float*)d_in[0];
    const float* W_in  = (const float*)d_in[1];
    const float* b_in  = (const float*)d_in[2];
    const float* W_h   = (const float*)d_in[3];
    const float* b_h   = (const float*)d_in[4];
    const float* W_out = (const float*)d_in[5];
    // d_in[6] = b_out: constant output offset, zero derivative -> unused

    double*         partials = (double*)((char*)d_ws + WS_PARTIALS);
    unsigned short* whi      = (unsigned short*)((char*)d_ws + WS_WHI);
    unsigned short* wlo      = (unsigned short*)((char*)d_ws + WS_WLO);
    float*          out      = (float*)d_out;

    const size_t lds_bytes = 2 * PLANE;  // 81920 B -> 2 WGs/CU (R7-proven)
    (void)hipFuncSetAttribute((const void*)pinn_mfma,
                              hipFuncAttributeMaxDynamicSharedMemorySize, (int)lds_bytes);

    hipLaunchKernelGGL(prep_w, dim3(512), dim3(64), 0, stream, W_h, whi, wlo);
    hipLaunchKernelGGL(pinn_mfma, dim3(NWG), dim3(512), lds_bytes, stream,
                       X, W_in, b_in, b_h, W_out, whi, wlo, partials);
    hipLaunchKernelGGL(pinn_reduce_kernel, dim3(1), dim3(256), 0, stream,
                       partials, out);
}